// Round 2
// baseline (154.335 us; speedup 1.0000x reference)
//
#include <hip/hip_runtime.h>
#include <math.h>

#define NFRM 4
#define NFACE 512
#define TT 256
#define REC 24
#define TANF32 0.413980342966f      // float32(tan(0.785/2))
#define LOG1M_CONST -9.21017456f    // float32(log1p(-float32(0.9999)))
#define D2_CUTOFF 0.004286f         // exp(-7000*d2) < 1.2e-13 beyond this

__device__ __forceinline__ float fm(float a, float b) { return __fmul_rn(a, b); }
__device__ __forceinline__ float fa2(float a, float b) { return __fadd_rn(a, b); }
__device__ __forceinline__ float fs2(float a, float b) { return __fsub_rn(a, b); }
__device__ __forceinline__ float fd2(float a, float b) { return __fdiv_rn(a, b); }

// ---------------- Kernel 1: per-(frame,face) geometry setup ----------------
// Record layout (REC=24 floats):
// [0]bx [1]by [2]e0x=cx-bx [3]e0y=cy-by
// [4]cx [5]cy [6]e1x=ax-cx [7]e1y=ay-cy
// [8]ax [9]ay [10]e2x=bx-ax [11]e2y=by-ay
// [12]inv_area [13]sgn(area) [14]flag [15]0
// [16]fz0 [17]fz1 [18]fz2 [19]0
// [20]invL(seg v0v1,e2) [21]invL(seg v1v2,e0) [22]invL(seg v2v0,e1) [23]0
__global__ void setup_kernel(const float* __restrict__ trans,
                             const float* __restrict__ quat,
                             const float* __restrict__ uverts,
                             const int* __restrict__ faces,
                             float* __restrict__ recs) {
    int idx = blockIdx.x * blockDim.x + threadIdx.x;
    if (idx >= NFRM * NFACE) return;
    int frame = idx >> 9;
    int face  = idx & (NFACE - 1);

    float qw = quat[frame * 4 + 0];
    float qx = quat[frame * 4 + 1];
    float qy = quat[frame * 4 + 2];
    float qz = quat[frame * 4 + 3];
    float qn = sqrtf(fa2(fa2(fa2(fm(qw, qw), fm(qx, qx)), fm(qy, qy)), fm(qz, qz)));
    qw = fd2(qw, qn); qx = fd2(qx, qn); qy = fd2(qy, qn); qz = fd2(qz, qn);

    float r00 = fs2(1.f, fm(2.f, fa2(fm(qy, qy), fm(qz, qz))));
    float r01 = fm(2.f, fs2(fm(qx, qy), fm(qw, qz)));
    float r02 = fm(2.f, fa2(fm(qx, qz), fm(qw, qy)));
    float r10 = fm(2.f, fa2(fm(qx, qy), fm(qw, qz)));
    float r11 = fs2(1.f, fm(2.f, fa2(fm(qx, qx), fm(qz, qz))));
    float r12 = fm(2.f, fs2(fm(qy, qz), fm(qw, qx)));
    float r20 = fm(2.f, fs2(fm(qx, qz), fm(qw, qy)));
    float r21 = fm(2.f, fa2(fm(qy, qz), fm(qw, qx)));
    float r22 = fs2(1.f, fm(2.f, fa2(fm(qx, qx), fm(qy, qy))));

    float tx = trans[frame * 3 + 0];
    float ty = trans[frame * 3 + 1];
    float tz = trans[frame * 3 + 2];

    float camx[3], camy[3], camz[3], ix[3], iy[3];
    for (int k = 0; k < 3; ++k) {
        int vi = faces[face * 3 + k];
        float ux = uverts[vi * 3 + 0];
        float uy = uverts[vi * 3 + 1];
        float uz = uverts[vi * 3 + 2];
        // np order: ((R_i0*u0 + R_i1*u1) + R_i2*u2) + t_i, then z-2
        float X = fa2(fa2(fa2(fm(r00, ux), fm(r01, uy)), fm(r02, uz)), tx);
        float Y = fa2(fa2(fa2(fm(r10, ux), fm(r11, uy)), fm(r12, uz)), ty);
        float Z = fs2(fa2(fa2(fa2(fm(r20, ux), fm(r21, uy)), fm(r22, uz)), tz), 2.0f);
        float negz = -Z;
        camx[k] = X; camy[k] = Y; camz[k] = Z;
        ix[k] = fd2(fd2(X, TANF32), negz);
        iy[k] = fd2(fd2(Y, TANF32), negz);
    }

    // back-face test: fnz>0 <=> nz>0 (denominator strictly positive)
    float e1x = fs2(camx[1], camx[0]), e1y = fs2(camy[1], camy[0]);
    float e2x = fs2(camx[2], camx[0]), e2y = fs2(camy[2], camy[0]);
    float nz = fs2(fm(e1x, e2y), fm(e1y, e2x));

    float ax = ix[0], ay = iy[0], bx = ix[1], by = iy[1], cx = ix[2], cy = iy[2];
    // area = (cx-ax)*(by-ay) - (cy-ay)*(bx-ax), np form
    float area = fs2(fm(fs2(cx, ax), fs2(by, ay)), fm(fs2(cy, ay), fs2(bx, ax)));
    bool areaok = fabsf(area) > 1e-10f;
    float area_s = (fabsf(area) < 1e-10f) ? 1e-10f : area;

    float e0x_ = fs2(cx, bx), e0y_ = fs2(cy, by);
    float e1x_ = fs2(ax, cx), e1y_ = fs2(ay, cy);
    float e2x_ = fs2(bx, ax), e2y_ = fs2(by, ay);

    float* r = recs + (size_t)idx * REC;
    r[0] = bx;  r[1] = by;  r[2] = e0x_;  r[3] = e0y_;
    r[4] = cx;  r[5] = cy;  r[6] = e1x_;  r[7] = e1y_;
    r[8] = ax;  r[9] = ay;  r[10] = e2x_; r[11] = e2y_;
    r[12] = fd2(1.0f, area_s);
    r[13] = (area_s >= 0.f) ? 1.f : -1.f;
    r[14] = (nz > 0.f) ? (areaok ? 1.f : 2.f) : 0.f;
    r[15] = 0.f;
    r[16] = camz[0]; r[17] = camz[1]; r[18] = camz[2]; r[19] = 0.f;
    r[20] = fd2(1.0f, fa2(fa2(fm(e2x_, e2x_), fm(e2y_, e2y_)), 1e-12f));
    r[21] = fd2(1.0f, fa2(fa2(fm(e0x_, e0x_), fm(e0y_, e0y_)), 1e-12f));
    r[22] = fd2(1.0f, fa2(fa2(fm(e1x_, e1x_), fm(e1y_, e1y_)), 1e-12f));
    r[23] = 0.f;
}

// ---------------- Kernel 2: rasterize + shade ----------------
// 1024 blocks; block = 256 threads = 64 pixels x 4 face-chunks.
__global__ __launch_bounds__(256, 2) void raster_kernel(
        const float* __restrict__ recs,
        const float* __restrict__ ffeat,
        const float* __restrict__ tex,
        float* __restrict__ out,
        float* __restrict__ softbuf) {
    __shared__ __align__(16) float lds[NFACE * REC];  // 48 KB
    __shared__ float s_score[256], s_w0[256], s_w1[256], s_w2[256], s_acc[256];
    __shared__ int s_best[256];

    int frame   = blockIdx.x >> 8;
    int tileIdx = blockIdx.x & 255;

    const float4* fr4 = (const float4*)(recs + (size_t)frame * NFACE * REC);
    float4* lds4 = (float4*)lds;
    for (int i = threadIdx.x; i < NFACE * REC / 4; i += 256) lds4[i] = fr4[i];
    __syncthreads();

    int chunk = threadIdx.x >> 6;
    int pix   = threadIdx.x & 63;
    int p = tileIdx * 64 + pix;
    int h = p >> 7, w = p & 127;
    float px = (w + 0.5f) * (1.0f / 64.0f) - 1.0f;   // exact, == np value
    float py = 1.0f - (h + 0.5f) * (1.0f / 64.0f);

    float bestScore = -1e30f;
    int best = -1;
    float bw0 = 0.f, bw1 = 0.f, bw2 = 0.f;
    float acc = 0.f;

    int f0 = chunk * (NFACE / 4), f1 = f0 + NFACE / 4;
    for (int f = f0; f < f1; ++f) {
        const float* r = lds + f * REC;
        float flag = r[14];
        if (flag == 0.f) continue;   // wave-uniform skip (fnz<=0)
        // numerators in np's exact expression form (sign-exact inside test)
        float n0 = fs2(fm(fs2(px, r[0]), r[3]), fm(fs2(py, r[1]), r[2]));
        float n1 = fs2(fm(fs2(px, r[4]), r[7]), fm(fs2(py, r[5]), r[6]));
        float n2 = fs2(fm(fs2(px, r[8]), r[11]), fm(fs2(py, r[9]), r[10]));
        float sgn = r[13];
        bool inside = (flag == 1.f) & (fm(n0, sgn) >= 0.f) & (fm(n1, sgn) >= 0.f)
                    & (fm(n2, sgn) >= 0.f);
        if (inside) {
            float ia = r[12];
            float w0 = fm(n0, ia), w1v = fm(n1, ia), w2v = fm(n2, ia);
            float zpix = fa2(fa2(fm(w0, r[16]), fm(w1v, r[17])), fm(w2v, r[18]));
            if (zpix > bestScore) {  // strict > == np argmax first-max
                bestScore = zpix; best = f; bw0 = w0; bw1 = w1v; bw2 = w2v;
            }
            acc += LOG1M_CONST;      // d2=0 -> prob=0.9999
        } else {
            // continuous path: fma allowed
            float apx = px - r[8], apy = py - r[9];          // seg v0->v1 (e2)
            float t0 = fminf(fmaxf((apx * r[10] + apy * r[11]) * r[20], 0.f), 1.f);
            float dx0 = apx - t0 * r[10], dy0 = apy - t0 * r[11];
            float d2 = dx0 * dx0 + dy0 * dy0;
            float bpx = px - r[0], bpy = py - r[1];          // seg v1->v2 (e0)
            float t1 = fminf(fmaxf((bpx * r[2] + bpy * r[3]) * r[21], 0.f), 1.f);
            float dx1 = bpx - t1 * r[2], dy1 = bpy - t1 * r[3];
            d2 = fminf(d2, dx1 * dx1 + dy1 * dy1);
            float cpx = px - r[4], cpy = py - r[5];          // seg v2->v0 (e1)
            float t2 = fminf(fmaxf((cpx * r[6] + cpy * r[7]) * r[22], 0.f), 1.f);
            float dx2 = cpx - t2 * r[6], dy2 = cpy - t2 * r[7];
            d2 = fminf(d2, dx2 * dx2 + dy2 * dy2);
            if (d2 < D2_CUTOFF) {
                float pr = fminf(expf(d2 * -7000.f), 0.9999f);
                acc += log1pf(-pr);
            }
        }
    }

    s_score[threadIdx.x] = bestScore;
    s_best[threadIdx.x] = best;
    s_w0[threadIdx.x] = bw0; s_w1[threadIdx.x] = bw1; s_w2[threadIdx.x] = bw2;
    s_acc[threadIdx.x] = acc;
    __syncthreads();

    if (threadIdx.x < 64) {
        int i = threadIdx.x;
        bestScore = s_score[i]; best = s_best[i];
        bw0 = s_w0[i]; bw1 = s_w1[i]; bw2 = s_w2[i];
        acc = s_acc[i];
        for (int c = 1; c < 4; ++c) {   // ascending chunk order keeps first-max
            int j = c * 64 + i;
            float sc = s_score[j];
            if (sc > bestScore) {
                bestScore = sc; best = s_best[j];
                bw0 = s_w0[j]; bw1 = s_w1[j]; bw2 = s_w2[j];
            }
            acc += s_acc[j];
        }
        float fu = 0.f, fv = 0.f;
        if (best >= 0) {
            const float* fb = ffeat + best * 6;
            fu = bw0 * fb[0] + bw1 * fb[2] + bw2 * fb[4];
            fv = bw0 * fb[1] + bw1 * fb[3] + bw2 * fb[5];
        }
        float u = fminf(fmaxf(fu, 0.f), 1.f);
        float v = fminf(fmaxf(fv, 0.f), 1.f);
        float x = u * (float)TT - 0.5f;
        float y = (1.0f - v) * (float)TT - 0.5f;
        float x0f = floorf(x), y0f = floorf(y);
        float wx = x - x0f, wy = y - y0f;
        int x0 = min(max((int)x0f, 0), TT - 1);
        int x1 = min(x0 + 1, TT - 1);
        int y0 = min(max((int)y0f, 0), TT - 1);
        int y1 = min(y0 + 1, TT - 1);
        size_t obase = (size_t)frame * 5 * 16384 + p;
        for (int c = 0; c < 3; ++c) {
            const float* tc = tex + c * (TT * TT);
            float t00 = tc[y0 * TT + x0];
            float t01 = tc[y0 * TT + x1];
            float t10 = tc[y1 * TT + x0];
            float t11 = tc[y1 * TT + x1];
            float rgb = (1.f - wy) * ((1.f - wx) * t00 + wx * t01)
                      + wy * ((1.f - wx) * t10 + wx * t11);
            out[obase + (size_t)c * 16384] = rgb;
        }
        int redw = (best >= 0) ? best : (NFACE - 1);
        const float* rr = lds + redw * REC;
        float depth = fd2(fa2(fa2(rr[16], rr[17]), rr[18]), 3.0f);
        out[obase + 4ull * 16384] = depth;
        float soft = 1.0f - expf(acc);
        softbuf[frame * 16384 + p] = soft;
    }
}

// ---------------- Kernel 3: 7x7 min-pool (pad = +inf identity) ----------------
__global__ void minpool_kernel(const float* __restrict__ softbuf,
                               float* __restrict__ out) {
    int idx = blockIdx.x * 256 + threadIdx.x;
    if (idx >= NFRM * 16384) return;
    int frame = idx >> 14;
    int p = idx & 16383;
    int h = p >> 7, w = p & 127;
    const float* sb = softbuf + frame * 16384;
    float m = INFINITY;
    int h0 = max(h - 3, 0), h1 = min(h + 3, 127);
    int w0 = max(w - 3, 0), w1 = min(w + 3, 127);
    for (int hh = h0; hh <= h1; ++hh)
        for (int ww = w0; ww <= w1; ++ww)
            m = fminf(m, sb[hh * 128 + ww]);
    out[(size_t)frame * 5 * 16384 + 3ull * 16384 + p] = m;
}

// ---------------- launch ----------------
extern "C" void kernel_launch(void* const* d_in, const int* in_sizes, int n_in,
                              void* d_out, int out_size, void* d_ws, size_t ws_size,
                              hipStream_t stream) {
    const float* trans  = (const float*)d_in[0]; // (1,1,4,3)
    const float* quat   = (const float*)d_in[1]; // (1,4,4)
    const float* uverts = (const float*)d_in[2]; // (1,256,3)
    const float* ffeat  = (const float*)d_in[3]; // (1,512,3,2)
    const float* tex    = (const float*)d_in[4]; // (1,3,256,256)
    const int*   faces  = (const int*)d_in[5];   // (512,3)
    float* out = (float*)d_out;                  // (1,4,1,5,128,128) fp32

    float* recs    = (float*)d_ws;               // 4*512*24 floats
    float* softbuf = recs + NFRM * NFACE * REC;  // 4*16384 floats

    setup_kernel<<<(NFRM * NFACE + 255) / 256, 256, 0, stream>>>(trans, quat, uverts, faces, recs);
    raster_kernel<<<NFRM * 256, 256, 0, stream>>>(recs, ffeat, tex, out, softbuf);
    minpool_kernel<<<NFRM * 16384 / 256, 256, 0, stream>>>(softbuf, out);
}

// Round 3
// 128.026 us; speedup vs baseline: 1.2055x; 1.2055x over previous
//
#include <hip/hip_runtime.h>
#include <math.h>

#define NFRM 4
#define NFACE 512
#define TT 256
#define REC 32                      // floats per face record (pow2 for addressing)
#define TANF32 0.413980342966f      // float32(tan(0.785/2))
#define LOG1M_CONST -9.21017456f    // float32(log1p(-float32(0.9999)))
#define D2_CUTOFF 0.004286f         // exp(-7000*d2) < 1.2e-13 beyond this
#define MARGIN 0.0656f              // MARGIN^2 = 0.004303 > D2_CUTOFF

__device__ __forceinline__ float fm(float a, float b) { return __fmul_rn(a, b); }
__device__ __forceinline__ float fa2(float a, float b) { return __fadd_rn(a, b); }
__device__ __forceinline__ float fs2(float a, float b) { return __fsub_rn(a, b); }
__device__ __forceinline__ float fd2(float a, float b) { return __fdiv_rn(a, b); }

// Record layout (REC=32):
// [0]xmin [1]xmax [2]ymin [3]ymax
// [4]flag (0=cull,1=ok,2=degenerate-area) [5]sgn(area) [6]inv_area [7]-
// [8]ax [9]ay [10]e2x=bx-ax [11]e2y=by-ay
// [12]bx [13]by [14]e0x=cx-bx [15]e0y=cy-by
// [16]cx [17]cy [18]e1x=ax-cx [19]e1y=ay-cy
// [20]fz0 [21]fz1 [22]fz2 [23]-
// [24]invL2(e2 seg v0v1) [25]invL2(e0 seg v1v2) [26]invL2(e1 seg v2v0) [27..31]-

// ---------------- Kernel 1: per-(frame,face) geometry setup ----------------
__global__ void setup_kernel(const float* __restrict__ trans,
                             const float* __restrict__ quat,
                             const float* __restrict__ uverts,
                             const int* __restrict__ faces,
                             float* __restrict__ recs) {
    int idx = blockIdx.x * blockDim.x + threadIdx.x;
    if (idx >= NFRM * NFACE) return;
    int frame = idx >> 9;
    int face  = idx & (NFACE - 1);

    float qw = quat[frame * 4 + 0];
    float qx = quat[frame * 4 + 1];
    float qy = quat[frame * 4 + 2];
    float qz = quat[frame * 4 + 3];
    float qn = sqrtf(fa2(fa2(fa2(fm(qw, qw), fm(qx, qx)), fm(qy, qy)), fm(qz, qz)));
    qw = fd2(qw, qn); qx = fd2(qx, qn); qy = fd2(qy, qn); qz = fd2(qz, qn);

    float r00 = fs2(1.f, fm(2.f, fa2(fm(qy, qy), fm(qz, qz))));
    float r01 = fm(2.f, fs2(fm(qx, qy), fm(qw, qz)));
    float r02 = fm(2.f, fa2(fm(qx, qz), fm(qw, qy)));
    float r10 = fm(2.f, fa2(fm(qx, qy), fm(qw, qz)));
    float r11 = fs2(1.f, fm(2.f, fa2(fm(qx, qx), fm(qz, qz))));
    float r12 = fm(2.f, fs2(fm(qy, qz), fm(qw, qx)));
    float r20 = fm(2.f, fs2(fm(qx, qz), fm(qw, qy)));
    float r21 = fm(2.f, fa2(fm(qy, qz), fm(qw, qx)));
    float r22 = fs2(1.f, fm(2.f, fa2(fm(qx, qx), fm(qy, qy))));

    float tx = trans[frame * 3 + 0];
    float ty = trans[frame * 3 + 1];
    float tz = trans[frame * 3 + 2];

    float camx[3], camy[3], camz[3], ix[3], iy[3];
    for (int k = 0; k < 3; ++k) {
        int vi = faces[face * 3 + k];
        float ux = uverts[vi * 3 + 0];
        float uy = uverts[vi * 3 + 1];
        float uz = uverts[vi * 3 + 2];
        float X = fa2(fa2(fa2(fm(r00, ux), fm(r01, uy)), fm(r02, uz)), tx);
        float Y = fa2(fa2(fa2(fm(r10, ux), fm(r11, uy)), fm(r12, uz)), ty);
        float Z = fs2(fa2(fa2(fa2(fm(r20, ux), fm(r21, uy)), fm(r22, uz)), tz), 2.0f);
        float negz = -Z;
        camx[k] = X; camy[k] = Y; camz[k] = Z;
        ix[k] = fd2(fd2(X, TANF32), negz);
        iy[k] = fd2(fd2(Y, TANF32), negz);
    }

    // back-face: fnz>0 <=> nz>0 (norm denominator strictly positive)
    float e1cx = fs2(camx[1], camx[0]), e1cy = fs2(camy[1], camy[0]);
    float e2cx = fs2(camx[2], camx[0]), e2cy = fs2(camy[2], camy[0]);
    float nz = fs2(fm(e1cx, e2cy), fm(e1cy, e2cx));

    float ax = ix[0], ay = iy[0], bx = ix[1], by = iy[1], cx = ix[2], cy = iy[2];
    float area = fs2(fm(fs2(cx, ax), fs2(by, ay)), fm(fs2(cy, ay), fs2(bx, ax)));
    bool areaok = fabsf(area) > 1e-10f;
    float area_s = (fabsf(area) < 1e-10f) ? 1e-10f : area;

    float e0x = fs2(cx, bx), e0y = fs2(cy, by);
    float e1x = fs2(ax, cx), e1y = fs2(ay, cy);
    float e2x = fs2(bx, ax), e2y = fs2(by, ay);

    float* r = recs + (size_t)idx * REC;
    r[0] = fminf(fminf(ax, bx), cx);
    r[1] = fmaxf(fmaxf(ax, bx), cx);
    r[2] = fminf(fminf(ay, by), cy);
    r[3] = fmaxf(fmaxf(ay, by), cy);
    r[4] = (nz > 0.f) ? (areaok ? 1.f : 2.f) : 0.f;
    r[5] = (area_s >= 0.f) ? 1.f : -1.f;
    r[6] = fd2(1.0f, area_s);
    r[7] = 0.f;
    r[8]  = ax; r[9]  = ay; r[10] = e2x; r[11] = e2y;
    r[12] = bx; r[13] = by; r[14] = e0x; r[15] = e0y;
    r[16] = cx; r[17] = cy; r[18] = e1x; r[19] = e1y;
    r[20] = camz[0]; r[21] = camz[1]; r[22] = camz[2]; r[23] = 0.f;
    r[24] = fd2(1.0f, fa2(fa2(fm(e2x, e2x), fm(e2y, e2y)), 1e-12f));
    r[25] = fd2(1.0f, fa2(fa2(fm(e0x, e0x), fm(e0y, e0y)), 1e-12f));
    r[26] = fd2(1.0f, fa2(fa2(fm(e1x, e1x), fm(e1y, e1y)), 1e-12f));
    r[27] = 0.f; r[28] = 0.f; r[29] = 0.f; r[30] = 0.f; r[31] = 0.f;
}

// ---------------- Kernel 2: rasterize + shade ----------------
// 1024 blocks; block = 256 threads = 64 pixels (8x8 tile) x 4 face-chunks.
// Face records are wave-uniform -> scalar loads; bbox+margin gives a
// wave-uniform skip of faces that provably contribute nothing.
__global__ __launch_bounds__(256, 4) void raster_kernel(
        const float* __restrict__ recs,
        const float* __restrict__ ffeat,
        const float* __restrict__ tex,
        float* __restrict__ out,
        float* __restrict__ softbuf) {
    __shared__ float s_score[256], s_w0[256], s_w1[256], s_w2[256], s_acc[256];
    __shared__ int s_best[256];

    int frame   = blockIdx.x >> 8;
    int tileIdx = blockIdx.x & 255;
    int txo = (tileIdx & 15) * 8;   // tile origin in pixels
    int tyo = (tileIdx >> 4) * 8;

    int chunk = threadIdx.x >> 6;
    int lane  = threadIdx.x & 63;
    int w = txo + (lane & 7);
    int h = tyo + (lane >> 3);
    int p = h * 128 + w;
    float px = (w + 0.5f) * (1.0f / 64.0f) - 1.0f;   // exact, == np value
    float py = 1.0f - (h + 0.5f) * (1.0f / 64.0f);

    // tile pixel-center extents (wave-uniform)
    float txmin = (txo + 0.5f) * (1.0f / 64.0f) - 1.0f - MARGIN;
    float txmax = (txo + 7.5f) * (1.0f / 64.0f) - 1.0f + MARGIN;
    float tymin = 1.0f - (tyo + 7.5f) * (1.0f / 64.0f) - MARGIN;
    float tymax = 1.0f - (tyo + 0.5f) * (1.0f / 64.0f) + MARGIN;

    const float* recF = recs + (size_t)frame * NFACE * REC;

    float bestScore = -1e30f;
    int best = -1;
    float bw0 = 0.f, bw1 = 0.f, bw2 = 0.f;
    float acc = 0.f;

    int f0 = chunk * (NFACE / 4), f1 = f0 + NFACE / 4;
    for (int f = f0; f < f1; ++f) {
        const float* r = recF + ((size_t)__builtin_amdgcn_readfirstlane(f) << 5);
        float flag = r[4];
        bool skip = (flag == 0.f) | (r[0] > txmax) | (r[1] < txmin)
                  | (r[2] > tymax) | (r[3] < tymin);
        if (__builtin_amdgcn_readfirstlane((int)skip)) continue;  // scalar branch

        float ax = r[8],  ay = r[9],  e2x = r[10], e2y = r[11];
        float bx = r[12], by = r[13], e0x = r[14], e0y = r[15];
        float cx = r[16], cy = r[17], e1x = r[18], e1y = r[19];
        float apx = fs2(px, ax), apy = fs2(py, ay);
        float bpx = fs2(px, bx), bpy = fs2(py, by);
        float cpx = fs2(px, cx), cpy = fs2(py, cy);
        // numerators in np's exact expression form (sign-exact inside test)
        float n0 = fs2(fm(bpx, e0y), fm(bpy, e0x));
        float n1 = fs2(fm(cpx, e1y), fm(cpy, e1x));
        float n2 = fs2(fm(apx, e2y), fm(apy, e2x));
        float sgn = r[5];
        bool inside = (flag == 1.f) & (fm(n0, sgn) >= 0.f)
                    & (fm(n1, sgn) >= 0.f) & (fm(n2, sgn) >= 0.f);
        if (inside) {
            float ia = r[6];
            float w0 = fm(n0, ia), w1v = fm(n1, ia), w2v = fm(n2, ia);
            float zpix = fa2(fa2(fm(w0, r[20]), fm(w1v, r[21])), fm(w2v, r[22]));
            if (zpix > bestScore) {  // strict > == np argmax first-max
                bestScore = zpix; best = f; bw0 = w0; bw1 = w1v; bw2 = w2v;
            }
            acc += LOG1M_CONST;      // d2=0 -> prob=0.9999
        } else {
            float t0 = fminf(fmaxf((apx * e2x + apy * e2y) * r[24], 0.f), 1.f);
            float dx0 = apx - t0 * e2x, dy0 = apy - t0 * e2y;
            float d2 = dx0 * dx0 + dy0 * dy0;
            float t1 = fminf(fmaxf((bpx * e0x + bpy * e0y) * r[25], 0.f), 1.f);
            float dx1 = bpx - t1 * e0x, dy1 = bpy - t1 * e0y;
            d2 = fminf(d2, dx1 * dx1 + dy1 * dy1);
            float t2 = fminf(fmaxf((cpx * e1x + cpy * e1y) * r[26], 0.f), 1.f);
            float dx2 = cpx - t2 * e1x, dy2 = cpy - t2 * e1y;
            d2 = fminf(d2, dx2 * dx2 + dy2 * dy2);
            if (d2 < D2_CUTOFF) {
                float pr = fminf(__expf(d2 * -7000.f), 0.9999f);
                acc += __logf(1.0f - pr);
            }
        }
    }

    s_score[threadIdx.x] = bestScore;
    s_best[threadIdx.x] = best;
    s_w0[threadIdx.x] = bw0; s_w1[threadIdx.x] = bw1; s_w2[threadIdx.x] = bw2;
    s_acc[threadIdx.x] = acc;
    __syncthreads();

    if (threadIdx.x < 64) {
        int i = threadIdx.x;   // chunk 0 thread: same pixel (p, px, py)
        bestScore = s_score[i]; best = s_best[i];
        bw0 = s_w0[i]; bw1 = s_w1[i]; bw2 = s_w2[i];
        acc = s_acc[i];
        for (int c = 1; c < 4; ++c) {   // ascending chunk order keeps first-max
            int j = c * 64 + i;
            float sc = s_score[j];
            if (sc > bestScore) {
                bestScore = sc; best = s_best[j];
                bw0 = s_w0[j]; bw1 = s_w1[j]; bw2 = s_w2[j];
            }
            acc += s_acc[j];
        }
        float fu = 0.f, fv = 0.f;
        if (best >= 0) {
            const float* fb = ffeat + best * 6;
            fu = bw0 * fb[0] + bw1 * fb[2] + bw2 * fb[4];
            fv = bw0 * fb[1] + bw1 * fb[3] + bw2 * fb[5];
        }
        float u = fminf(fmaxf(fu, 0.f), 1.f);
        float v = fminf(fmaxf(fv, 0.f), 1.f);
        float x = u * (float)TT - 0.5f;
        float y = (1.0f - v) * (float)TT - 0.5f;
        float x0f = floorf(x), y0f = floorf(y);
        float wx = x - x0f, wy = y - y0f;
        int x0 = min(max((int)x0f, 0), TT - 1);
        int x1 = min(x0 + 1, TT - 1);
        int y0 = min(max((int)y0f, 0), TT - 1);
        int y1 = min(y0 + 1, TT - 1);
        size_t obase = (size_t)frame * 5 * 16384 + p;
        for (int c = 0; c < 3; ++c) {
            const float* tc = tex + c * (TT * TT);
            float t00 = tc[y0 * TT + x0];
            float t01 = tc[y0 * TT + x1];
            float t10 = tc[y1 * TT + x0];
            float t11 = tc[y1 * TT + x1];
            float rgb = (1.f - wy) * ((1.f - wx) * t00 + wx * t01)
                      + wy * ((1.f - wx) * t10 + wx * t11);
            out[obase + (size_t)c * 16384] = rgb;
        }
        int redw = (best >= 0) ? best : (NFACE - 1);
        const float* rr = recF + ((size_t)redw << 5);
        float depth = fd2(fa2(fa2(rr[20], rr[21]), rr[22]), 3.0f);
        out[obase + 4ull * 16384] = depth;
        float soft = 1.0f - __expf(acc);
        softbuf[frame * 16384 + p] = soft;
    }
}

// ---------------- Kernel 3: 7x7 min-pool (pad = +inf identity) ----------------
__global__ void minpool_kernel(const float* __restrict__ softbuf,
                               float* __restrict__ out) {
    int idx = blockIdx.x * 256 + threadIdx.x;
    if (idx >= NFRM * 16384) return;
    int frame = idx >> 14;
    int p = idx & 16383;
    int h = p >> 7, w = p & 127;
    const float* sb = softbuf + frame * 16384;
    float m = INFINITY;
    int h0 = max(h - 3, 0), h1 = min(h + 3, 127);
    int w0 = max(w - 3, 0), w1 = min(w + 3, 127);
    for (int hh = h0; hh <= h1; ++hh)
        for (int ww = w0; ww <= w1; ++ww)
            m = fminf(m, sb[hh * 128 + ww]);
    out[(size_t)frame * 5 * 16384 + 3ull * 16384 + p] = m;
}

// ---------------- launch ----------------
extern "C" void kernel_launch(void* const* d_in, const int* in_sizes, int n_in,
                              void* d_out, int out_size, void* d_ws, size_t ws_size,
                              hipStream_t stream) {
    const float* trans  = (const float*)d_in[0]; // (1,1,4,3)
    const float* quat   = (const float*)d_in[1]; // (1,4,4)
    const float* uverts = (const float*)d_in[2]; // (1,256,3)
    const float* ffeat  = (const float*)d_in[3]; // (1,512,3,2)
    const float* tex    = (const float*)d_in[4]; // (1,3,256,256)
    const int*   faces  = (const int*)d_in[5];   // (512,3)
    float* out = (float*)d_out;                  // (1,4,1,5,128,128) fp32

    float* recs    = (float*)d_ws;               // 4*512*32 floats = 256 KB
    float* softbuf = recs + NFRM * NFACE * REC;  // 4*16384 floats

    setup_kernel<<<(NFRM * NFACE + 255) / 256, 256, 0, stream>>>(trans, quat, uverts, faces, recs);
    raster_kernel<<<NFRM * 256, 256, 0, stream>>>(recs, ffeat, tex, out, softbuf);
    minpool_kernel<<<NFRM * 16384 / 256, 256, 0, stream>>>(softbuf, out);
}

// Round 4
// 95.849 us; speedup vs baseline: 1.6102x; 1.3357x over previous
//
#include <hip/hip_runtime.h>
#include <math.h>

#define NFRM 4
#define NFACE 512
#define TT 256
#define REC 32                      // floats per face record (pow2 for addressing)
#define TANF32 0.413980342966f      // float32(tan(0.785/2))
#define LOG1M_CONST -9.21017456f    // float32(log1p(-float32(0.9999)))
#define D2_CUTOFF 0.004286f         // exp(-7000*d2) < 1.2e-13 beyond this
#define MARGIN 0.0656f              // MARGIN^2 = 0.004303 > D2_CUTOFF

__device__ __forceinline__ float fm(float a, float b) { return __fmul_rn(a, b); }
__device__ __forceinline__ float fa2(float a, float b) { return __fadd_rn(a, b); }
__device__ __forceinline__ float fs2(float a, float b) { return __fsub_rn(a, b); }
__device__ __forceinline__ float fd2(float a, float b) { return __fdiv_rn(a, b); }

// Record layout (REC=32):
// [4]flag (1=ok,2=degenerate-area) [5]sgn(area) [6]inv_area
// [8]ax [9]ay [10]e2x [11]e2y  [12]bx [13]by [14]e0x [15]e0y
// [16]cx [17]cy [18]e1x [19]e1y [20]fz0 [21]fz1 [22]fz2
// [24]invL2(e2) [25]invL2(e0) [26]invL2(e1)
// bbox4 array: (xmin,xmax,ymin,ymax); culled faces get an impossible bbox.

// ---------------- Kernel 1: per-(frame,face) geometry setup ----------------
__global__ void setup_kernel(const float* __restrict__ trans,
                             const float* __restrict__ quat,
                             const float* __restrict__ uverts,
                             const int* __restrict__ faces,
                             float* __restrict__ recs,
                             float4* __restrict__ bbox4) {
    int idx = blockIdx.x * blockDim.x + threadIdx.x;
    if (idx >= NFRM * NFACE) return;
    int frame = idx >> 9;
    int face  = idx & (NFACE - 1);

    float qw = quat[frame * 4 + 0];
    float qx = quat[frame * 4 + 1];
    float qy = quat[frame * 4 + 2];
    float qz = quat[frame * 4 + 3];
    float qn = sqrtf(fa2(fa2(fa2(fm(qw, qw), fm(qx, qx)), fm(qy, qy)), fm(qz, qz)));
    qw = fd2(qw, qn); qx = fd2(qx, qn); qy = fd2(qy, qn); qz = fd2(qz, qn);

    float r00 = fs2(1.f, fm(2.f, fa2(fm(qy, qy), fm(qz, qz))));
    float r01 = fm(2.f, fs2(fm(qx, qy), fm(qw, qz)));
    float r02 = fm(2.f, fa2(fm(qx, qz), fm(qw, qy)));
    float r10 = fm(2.f, fa2(fm(qx, qy), fm(qw, qz)));
    float r11 = fs2(1.f, fm(2.f, fa2(fm(qx, qx), fm(qz, qz))));
    float r12 = fm(2.f, fs2(fm(qy, qz), fm(qw, qx)));
    float r20 = fm(2.f, fs2(fm(qx, qz), fm(qw, qy)));
    float r21 = fm(2.f, fa2(fm(qy, qz), fm(qw, qx)));
    float r22 = fs2(1.f, fm(2.f, fa2(fm(qx, qx), fm(qy, qy))));

    float tx = trans[frame * 3 + 0];
    float ty = trans[frame * 3 + 1];
    float tz = trans[frame * 3 + 2];

    float camx[3], camy[3], camz[3], ix[3], iy[3];
    for (int k = 0; k < 3; ++k) {
        int vi = faces[face * 3 + k];
        float ux = uverts[vi * 3 + 0];
        float uy = uverts[vi * 3 + 1];
        float uz = uverts[vi * 3 + 2];
        float X = fa2(fa2(fa2(fm(r00, ux), fm(r01, uy)), fm(r02, uz)), tx);
        float Y = fa2(fa2(fa2(fm(r10, ux), fm(r11, uy)), fm(r12, uz)), ty);
        float Z = fs2(fa2(fa2(fa2(fm(r20, ux), fm(r21, uy)), fm(r22, uz)), tz), 2.0f);
        float negz = -Z;
        camx[k] = X; camy[k] = Y; camz[k] = Z;
        ix[k] = fd2(fd2(X, TANF32), negz);
        iy[k] = fd2(fd2(Y, TANF32), negz);
    }

    // back-face: fnz>0 <=> nz>0 (norm denominator strictly positive)
    float e1cx = fs2(camx[1], camx[0]), e1cy = fs2(camy[1], camy[0]);
    float e2cx = fs2(camx[2], camx[0]), e2cy = fs2(camy[2], camy[0]);
    float nz = fs2(fm(e1cx, e2cy), fm(e1cy, e2cx));

    float ax = ix[0], ay = iy[0], bx = ix[1], by = iy[1], cx = ix[2], cy = iy[2];
    float area = fs2(fm(fs2(cx, ax), fs2(by, ay)), fm(fs2(cy, ay), fs2(bx, ax)));
    bool areaok = fabsf(area) > 1e-10f;
    float area_s = (fabsf(area) < 1e-10f) ? 1e-10f : area;

    float e0x = fs2(cx, bx), e0y = fs2(cy, by);
    float e1x = fs2(ax, cx), e1y = fs2(ay, cy);
    float e2x = fs2(bx, ax), e2y = fs2(by, ay);

    float* r = recs + (size_t)idx * REC;
    r[0] = 0.f; r[1] = 0.f; r[2] = 0.f; r[3] = 0.f;
    r[4] = areaok ? 1.f : 2.f;
    r[5] = (area_s >= 0.f) ? 1.f : -1.f;
    r[6] = fd2(1.0f, area_s);
    r[7] = 0.f;
    r[8]  = ax; r[9]  = ay; r[10] = e2x; r[11] = e2y;
    r[12] = bx; r[13] = by; r[14] = e0x; r[15] = e0y;
    r[16] = cx; r[17] = cy; r[18] = e1x; r[19] = e1y;
    r[20] = camz[0]; r[21] = camz[1]; r[22] = camz[2]; r[23] = 0.f;
    r[24] = fd2(1.0f, fa2(fa2(fm(e2x, e2x), fm(e2y, e2y)), 1e-12f));
    r[25] = fd2(1.0f, fa2(fa2(fm(e0x, e0x), fm(e0y, e0y)), 1e-12f));
    r[26] = fd2(1.0f, fa2(fa2(fm(e1x, e1x), fm(e1y, e1y)), 1e-12f));
    r[27] = 0.f; r[28] = 0.f; r[29] = 0.f; r[30] = 0.f; r[31] = 0.f;

    float4 bb;
    if (nz > 0.f) {
        bb.x = fminf(fminf(ax, bx), cx);
        bb.y = fmaxf(fmaxf(ax, bx), cx);
        bb.z = fminf(fminf(ay, by), cy);
        bb.w = fmaxf(fmaxf(ay, by), cy);
    } else {  // culled: impossible bbox, never passes the tile test
        bb.x = 1e30f; bb.y = -1e30f; bb.z = 1e30f; bb.w = -1e30f;
    }
    bbox4[idx] = bb;
}

// ---------------- Kernel 2: rasterize + shade ----------------
// 1024 blocks; block = 256 threads = 64 pixels (8x8 tile) x 4 waves.
// Phase 1: ballot-compact the faces whose bbox+margin hits this tile into an
// order-preserving LDS list. Phase 2: waves split the list contiguously and
// evenly; loop body is branch-light so scalar record loads pipeline.
__global__ __launch_bounds__(256, 4) void raster_kernel(
        const float* __restrict__ recs,
        const float4* __restrict__ bbox4,
        const float* __restrict__ ffeat,
        const float* __restrict__ tex,
        float* __restrict__ out,
        float* __restrict__ softbuf) {
    __shared__ int s_list[NFACE];
    __shared__ int s_cnt[4];
    __shared__ float s_score[256], s_w0[256], s_w1[256], s_w2[256], s_acc[256];
    __shared__ int s_best[256];

    int frame   = blockIdx.x >> 8;
    int tileIdx = blockIdx.x & 255;
    int txo = (tileIdx & 15) * 8;
    int tyo = (tileIdx >> 4) * 8;

    int chunk = threadIdx.x >> 6;
    int lane  = threadIdx.x & 63;
    int w = txo + (lane & 7);
    int h = tyo + (lane >> 3);
    int p = h * 128 + w;
    float px = (w + 0.5f) * (1.0f / 64.0f) - 1.0f;   // exact, == np value
    float py = 1.0f - (h + 0.5f) * (1.0f / 64.0f);

    float txmin = (txo + 0.5f) * (1.0f / 64.0f) - 1.0f - MARGIN;
    float txmax = (txo + 7.5f) * (1.0f / 64.0f) - 1.0f + MARGIN;
    float tymin = 1.0f - (tyo + 7.5f) * (1.0f / 64.0f) - MARGIN;
    float tymax = 1.0f - (tyo + 0.5f) * (1.0f / 64.0f) + MARGIN;

    // ---- Phase 1: bin faces into s_list (ascending face order) ----
    const float4* bbF = bbox4 + frame * NFACE;
    unsigned long long m0, m1;
    {
        float4 b0 = bbF[chunk * 128 + lane];
        float4 b1 = bbF[chunk * 128 + 64 + lane];
        bool p0 = (b0.x <= txmax) & (b0.y >= txmin) & (b0.z <= tymax) & (b0.w >= tymin);
        bool p1 = (b1.x <= txmax) & (b1.y >= txmin) & (b1.z <= tymax) & (b1.w >= tymin);
        m0 = __ballot(p0);
        m1 = __ballot(p1);
    }
    if (lane == 0) s_cnt[chunk] = __popcll(m0) + __popcll(m1);
    __syncthreads();
    int base = 0;
    for (int c = 0; c < chunk; ++c) base += s_cnt[c];
    int total = s_cnt[0] + s_cnt[1] + s_cnt[2] + s_cnt[3];
    unsigned long long ltmask = (1ull << lane) - 1ull;
    if ((m0 >> lane) & 1)
        s_list[base + __popcll(m0 & ltmask)] = chunk * 128 + lane;
    if ((m1 >> lane) & 1)
        s_list[base + __popcll(m0) + __popcll(m1 & ltmask)] = chunk * 128 + 64 + lane;
    __syncthreads();

    // ---- Phase 2: process list chunk [lo,hi) (contiguous, ascending) ----
    const float* recF = recs + (size_t)frame * NFACE * REC;
    float bestScore = -1e30f;
    int best = -1;
    float bw0 = 0.f, bw1 = 0.f, bw2 = 0.f;
    float acc = 0.f;

    int lo = (total * chunk) >> 2;
    int hi = (total * (chunk + 1)) >> 2;
    #pragma unroll 2
    for (int i = lo; i < hi; ++i) {
        int f = __builtin_amdgcn_readfirstlane(s_list[i]);
        const float* r = recF + ((size_t)f << 5);
        float flag = r[4];
        float ax = r[8],  ay = r[9],  e2x = r[10], e2y = r[11];
        float bx = r[12], by = r[13], e0x = r[14], e0y = r[15];
        float cx = r[16], cy = r[17], e1x = r[18], e1y = r[19];
        float apx = fs2(px, ax), apy = fs2(py, ay);
        float bpx = fs2(px, bx), bpy = fs2(py, by);
        float cpx = fs2(px, cx), cpy = fs2(py, cy);
        // numerators in np's exact expression form (sign-exact inside test)
        float n0 = fs2(fm(bpx, e0y), fm(bpy, e0x));
        float n1 = fs2(fm(cpx, e1y), fm(cpy, e1x));
        float n2 = fs2(fm(apx, e2y), fm(apy, e2x));
        float sgn = r[5];
        bool inside = (flag == 1.f) & (fm(n0, sgn) >= 0.f)
                    & (fm(n1, sgn) >= 0.f) & (fm(n2, sgn) >= 0.f);
        if (inside) {
            float ia = r[6];
            float w0 = fm(n0, ia), w1v = fm(n1, ia), w2v = fm(n2, ia);
            float zpix = fa2(fa2(fm(w0, r[20]), fm(w1v, r[21])), fm(w2v, r[22]));
            if (zpix > bestScore) {  // strict > == np argmax first-max
                bestScore = zpix; best = f; bw0 = w0; bw1 = w1v; bw2 = w2v;
            }
            acc += LOG1M_CONST;      // d2=0 -> prob=0.9999
        } else {
            float t0 = fminf(fmaxf((apx * e2x + apy * e2y) * r[24], 0.f), 1.f);
            float dx0 = apx - t0 * e2x, dy0 = apy - t0 * e2y;
            float d2 = dx0 * dx0 + dy0 * dy0;
            float t1 = fminf(fmaxf((bpx * e0x + bpy * e0y) * r[25], 0.f), 1.f);
            float dx1 = bpx - t1 * e0x, dy1 = bpy - t1 * e0y;
            d2 = fminf(d2, dx1 * dx1 + dy1 * dy1);
            float t2 = fminf(fmaxf((cpx * e1x + cpy * e1y) * r[26], 0.f), 1.f);
            float dx2 = cpx - t2 * e1x, dy2 = cpy - t2 * e1y;
            d2 = fminf(d2, dx2 * dx2 + dy2 * dy2);
            if (d2 < D2_CUTOFF) {
                float pr = fminf(__expf(d2 * -7000.f), 0.9999f);
                acc += __logf(1.0f - pr);
            }
        }
    }

    s_score[threadIdx.x] = bestScore;
    s_best[threadIdx.x] = best;
    s_w0[threadIdx.x] = bw0; s_w1[threadIdx.x] = bw1; s_w2[threadIdx.x] = bw2;
    s_acc[threadIdx.x] = acc;
    __syncthreads();

    if (threadIdx.x < 64) {
        int i = threadIdx.x;   // chunk-0 thread: same pixel (p, px, py)
        bestScore = s_score[i]; best = s_best[i];
        bw0 = s_w0[i]; bw1 = s_w1[i]; bw2 = s_w2[i];
        acc = s_acc[i];
        for (int c = 1; c < 4; ++c) {   // ascending chunk order keeps first-max
            int j = c * 64 + i;
            float sc = s_score[j];
            if (sc > bestScore) {
                bestScore = sc; best = s_best[j];
                bw0 = s_w0[j]; bw1 = s_w1[j]; bw2 = s_w2[j];
            }
            acc += s_acc[j];
        }
        float fu = 0.f, fv = 0.f;
        if (best >= 0) {
            const float* fb = ffeat + best * 6;
            fu = bw0 * fb[0] + bw1 * fb[2] + bw2 * fb[4];
            fv = bw0 * fb[1] + bw1 * fb[3] + bw2 * fb[5];
        }
        float u = fminf(fmaxf(fu, 0.f), 1.f);
        float v = fminf(fmaxf(fv, 0.f), 1.f);
        float x = u * (float)TT - 0.5f;
        float y = (1.0f - v) * (float)TT - 0.5f;
        float x0f = floorf(x), y0f = floorf(y);
        float wx = x - x0f, wy = y - y0f;
        int x0 = min(max((int)x0f, 0), TT - 1);
        int x1 = min(x0 + 1, TT - 1);
        int y0 = min(max((int)y0f, 0), TT - 1);
        int y1 = min(y0 + 1, TT - 1);
        size_t obase = (size_t)frame * 5 * 16384 + p;
        for (int c = 0; c < 3; ++c) {
            const float* tc = tex + c * (TT * TT);
            float t00 = tc[y0 * TT + x0];
            float t01 = tc[y0 * TT + x1];
            float t10 = tc[y1 * TT + x0];
            float t11 = tc[y1 * TT + x1];
            float rgb = (1.f - wy) * ((1.f - wx) * t00 + wx * t01)
                      + wy * ((1.f - wx) * t10 + wx * t11);
            out[obase + (size_t)c * 16384] = rgb;
        }
        int redw = (best >= 0) ? best : (NFACE - 1);
        const float* rr = recF + ((size_t)redw << 5);
        float depth = fd2(fa2(fa2(rr[20], rr[21]), rr[22]), 3.0f);
        out[obase + 4ull * 16384] = depth;
        float soft = 1.0f - __expf(acc);
        softbuf[frame * 16384 + p] = soft;
    }
}

// ---------------- Kernel 3: 7x7 min-pool (pad = +inf identity) ----------------
__global__ void minpool_kernel(const float* __restrict__ softbuf,
                               float* __restrict__ out) {
    int idx = blockIdx.x * 256 + threadIdx.x;
    if (idx >= NFRM * 16384) return;
    int frame = idx >> 14;
    int p = idx & 16383;
    int h = p >> 7, w = p & 127;
    const float* sb = softbuf + frame * 16384;
    float m = INFINITY;
    int h0 = max(h - 3, 0), h1 = min(h + 3, 127);
    int w0 = max(w - 3, 0), w1 = min(w + 3, 127);
    for (int hh = h0; hh <= h1; ++hh)
        for (int ww = w0; ww <= w1; ++ww)
            m = fminf(m, sb[hh * 128 + ww]);
    out[(size_t)frame * 5 * 16384 + 3ull * 16384 + p] = m;
}

// ---------------- launch ----------------
extern "C" void kernel_launch(void* const* d_in, const int* in_sizes, int n_in,
                              void* d_out, int out_size, void* d_ws, size_t ws_size,
                              hipStream_t stream) {
    const float* trans  = (const float*)d_in[0]; // (1,1,4,3)
    const float* quat   = (const float*)d_in[1]; // (1,4,4)
    const float* uverts = (const float*)d_in[2]; // (1,256,3)
    const float* ffeat  = (const float*)d_in[3]; // (1,512,3,2)
    const float* tex    = (const float*)d_in[4]; // (1,3,256,256)
    const int*   faces  = (const int*)d_in[5];   // (512,3)
    float* out = (float*)d_out;                  // (1,4,1,5,128,128) fp32

    float* recs    = (float*)d_ws;                    // 4*512*32 floats = 256 KB
    float4* bbox4  = (float4*)(recs + NFRM * NFACE * REC);  // 4*512 float4 = 32 KB
    float* softbuf = (float*)(bbox4 + NFRM * NFACE);  // 4*16384 floats

    setup_kernel<<<(NFRM * NFACE + 255) / 256, 256, 0, stream>>>(trans, quat, uverts, faces, recs, bbox4);
    raster_kernel<<<NFRM * 256, 256, 0, stream>>>(recs, bbox4, ffeat, tex, out, softbuf);
    minpool_kernel<<<NFRM * 16384 / 256, 256, 0, stream>>>(softbuf, out);
}